// Round 22
// baseline (6559.536 us; speedup 1.0000x reference)
//
#include <hip/hip_runtime.h>

// ---------------------------------------------------------------------------
// LSTM scan, B=64 L=512 D=1024. Round 22 = R21 (512-step-kernel graph, 3.55ms,
// new best) with ONE change: batch-fused step kernel.
//   R21's step re-read Wr with 4x replication (4 b-groups x same 48 cols =
//   25MB/step from LLC). R22: 64 WGs x 512 thr, each WG = 16 d-cols x ALL 64
//   batches -> Wr read = 6.3MB/step (minimum), grid 4x smaller (faster
//   dispatch/drain). MFMAs/wave 24->48 (MfmaUtil ~2.5%, free).
//   LDS part[4][4][48][21] = 64512B (R19-proven pad-21 bank layout).
// Everything else identical to R21: kernel boundary = barrier, h ping-pong
// via args, c in-place re-seeded per call, xproj GEMM, no atomics anywhere.
// ---------------------------------------------------------------------------

typedef float    f32x4 __attribute__((ext_vector_type(4)));
typedef _Float16 half8 __attribute__((ext_vector_type(8)));
typedef _Float16 half4 __attribute__((ext_vector_type(4)));

#define AS1 __attribute__((address_space(1)))
#define AS3 __attribute__((address_space(3)))

#define B_  64
#define L_  512
#define D_  1024
#define N3_ 3072

// ws layout (bytes)
#define WKT_OFF   0LL          // f16 [3072][1024]   6291456
#define WRT_OFF   6291456LL    // f16 [3072][1024]   6291456
#define XH_OFF    12582912LL   // f16 [B*L][1024]   67108864
#define H16_OFF   79691776LL   // f16 [2][64][1024]   262144
#define CST_OFF   79953920LL   // f32 [64][1024]      262144
#define XPROJ_OFF 80216064LL   // f16 [B*L][3072]   201326592

__device__ __forceinline__ float sigmoidf_fast(float x) {
  return __builtin_amdgcn_rcpf(1.f + __builtin_amdgcn_exp2f(-1.4426950408889634f * x));
}
__device__ __forceinline__ float tanhf_fast(float x) {
  return 1.f - 2.f * __builtin_amdgcn_rcpf(1.f + __builtin_amdgcn_exp2f(2.8853900817779268f * x));
}

__device__ __forceinline__ void gload_lds16(const void* g, void* l) {
  __builtin_amdgcn_global_load_lds((const AS1 unsigned int*)g,
                                   (AS3 unsigned int*)l, 16, 0, 0);
}

// ---------------- prep: transpose + f32->f16 (Wk and Wr) -------------------
__global__ __launch_bounds__(256) void transpose_f16(
    const float* __restrict__ Wk, const float* __restrict__ Wr,
    _Float16* __restrict__ WkT, _Float16* __restrict__ WrT)
{
  __shared__ float tile[32][33];
  int b = blockIdx.x;
  const float* in = Wk; _Float16* outp = WkT;
  if (b >= 3072) { b -= 3072; in = Wr; outp = WrT; }
  const int n0 = (b % 96) * 32;
  const int k0 = (b / 96) * 32;
  const int tx = threadIdx.x & 31, ty = threadIdx.x >> 5;
#pragma unroll
  for (int i = 0; i < 32; i += 8)
    tile[ty + i][tx] = in[(size_t)(k0 + ty + i) * N3_ + n0 + tx];
  __syncthreads();
#pragma unroll
  for (int i = 0; i < 32; i += 8)
    outp[(size_t)(n0 + ty + i) * D_ + k0 + tx] = (_Float16)tile[tx][ty + i];
}

// ---------------- prep: x -> f16, h0 -> BOTH h16 buffers, c0 -> cst --------
__global__ void convert_inputs(const f32x4* __restrict__ x, const f32x4* __restrict__ h0,
                               const f32x4* __restrict__ c0,
                               half4* __restrict__ xh, half4* __restrict__ h16a,
                               half4* __restrict__ h16b, f32x4* __restrict__ cst)
{
  const int NX = (B_ * L_ * D_) / 4;
  const int NH = (B_ * D_) / 4;
  for (int i = blockIdx.x * blockDim.x + threadIdx.x; i < NX + NH;
       i += gridDim.x * blockDim.x) {
    if (i < NX) {
      xh[i] = __builtin_convertvector(x[i], half4);
    } else {
      const int k = i - NX;
      half4 v = __builtin_convertvector(h0[k], half4);
      h16a[k] = v;
      h16b[k] = v;
      cst[k] = c0[k];          // re-seed c every call (in-place updates)
    }
  }
}

// ---------------- xproj GEMM (R7-fixed swizzle, replay-proven) -------------
__global__ __launch_bounds__(256) void gemm_xproj(
    const _Float16* __restrict__ A,    // [32768][1024]
    const _Float16* __restrict__ BT,   // [3072][1024]
    _Float16* __restrict__ C)          // [32768][3072] f16
{
  __shared__ _Float16 As[128 * 32];
  __shared__ _Float16 Bs[128 * 32];
  const int tid = threadIdx.x, wave = tid >> 6, lane = tid & 63;
  const int mt = blockIdx.x / 24, ntile = blockIdx.x % 24;
  const int m0 = mt * 128, n0 = ntile * 128;
  const int l15 = lane & 15, l4h = lane >> 4;
  const int wm = (wave >> 1) * 64, wn = (wave & 1) * 64;

  const int c0i = wave * 2;
  const int lrow = lane >> 2;                       // 0..15 within chunk
  const int skel = 8 * ((lane & 3) ^ (lrow & 3));   // 2-bit XOR, in-bounds

  f32x4 acc[4][4];
#pragma unroll
  for (int i = 0; i < 4; ++i)
#pragma unroll
    for (int j = 0; j < 4; ++j) { f32x4 z = {0.f,0.f,0.f,0.f}; acc[i][j] = z; }

  for (int kk = 0; kk < 32; ++kk) {
    __syncthreads();
#pragma unroll
    for (int i = 0; i < 2; ++i) {
      const int c = c0i + i;
      const int row = c * 16 + lrow;
      gload_lds16(A  + (((size_t)(m0 + row)) << 10) + (kk << 5) + skel, &As[c << 9]);
      gload_lds16(BT + (((size_t)(n0 + row)) << 10) + (kk << 5) + skel, &Bs[c << 9]);
    }
    __syncthreads();
    half8 af[4], bf[4];
#pragma unroll
    for (int i = 0; i < 4; ++i) {
      const int ar = wm + i * 16 + l15;
      af[i] = *(const half8*)&As[(ar << 5) + ((l4h ^ (ar & 3)) << 3)];
      const int br = wn + i * 16 + l15;
      bf[i] = *(const half8*)&Bs[(br << 5) + ((l4h ^ (br & 3)) << 3)];
    }
#pragma unroll
    for (int i = 0; i < 4; ++i)
#pragma unroll
      for (int j = 0; j < 4; ++j)
        acc[i][j] = __builtin_amdgcn_mfma_f32_16x16x32_f16(af[i], bf[j], acc[i][j], 0, 0, 0);
  }
#pragma unroll
  for (int i = 0; i < 4; ++i) {
    const int row = m0 + wm + i * 16 + l4h * 4;
#pragma unroll
    for (int j = 0; j < 4; ++j) {
      const int col = n0 + wn + j * 16 + l15;
      _Float16* cp = C + (size_t)row * N3_ + col;
#pragma unroll
      for (int r = 0; r < 4; ++r)
        __builtin_nontemporal_store((_Float16)acc[i][j][r], cp + (size_t)r * N3_);
    }
  }
}

// ---------------- one scan step (kernel boundary = barrier) ----------------
// 64 WGs (d-slices of 16 cols) x 512 thr (8 waves). Wave w: ks = w&3
// (K-slice 256), bh = w>>2 (batch-half 32 -> 2 m-blocks of 16).
__global__ __launch_bounds__(512) void lstm_step(
    const _Float16* __restrict__ WrT,   // [3072][1024]
    const _Float16* __restrict__ xproj, // [B*L][3072]
    float*          __restrict__ cst,   // [64][1024] in-place
    float*          __restrict__ out,   // [64][512][1024]
    const _Float16* __restrict__ hc,    // h_t
    _Float16*       __restrict__ hn,    // h_{t+1}
    int t)
{
  const int tid = threadIdx.x, wave = tid >> 6, lane = tid & 63;
  const int d0 = blockIdx.x * 16;
  const int l15 = lane & 15, l4h = lane >> 4;
  const int ks = wave & 3, bh = wave >> 2;
  const int kbase = ks * 256;

  // Wr fragments (plain loads; L2/LLC-hot after step 0). 48 cols x 256k/wave.
  half8 Wrf[3][8];
#pragma unroll
  for (int g = 0; g < 3; ++g) {
    const _Float16* rr = WrT + (size_t)(g * D_ + d0 + l15) * D_ + kbase + l4h * 8;
#pragma unroll
    for (int kt = 0; kt < 8; ++kt) Wrf[g][kt] = *(const half8*)(rr + kt * 32);
  }

  // h fragments: 2 batch-blocks of 16 for this wave's batch-half
  half8 af[2][8];
#pragma unroll
  for (int mb = 0; mb < 2; ++mb) {
    const _Float16* hrow = hc + (size_t)(bh * 32 + mb * 16 + l15) * D_ + kbase + l4h * 8;
#pragma unroll
    for (int kt = 0; kt < 8; ++kt) af[mb][kt] = *(const half8*)(hrow + kt * 32);
  }

  f32x4 acc[2][3];
#pragma unroll
  for (int mb = 0; mb < 2; ++mb)
#pragma unroll
    for (int g = 0; g < 3; ++g) { f32x4 z = {0.f,0.f,0.f,0.f}; acc[mb][g] = z; }
#pragma unroll
  for (int kt = 0; kt < 8; ++kt)
#pragma unroll
    for (int mb = 0; mb < 2; ++mb)
#pragma unroll
      for (int g = 0; g < 3; ++g)
        acc[mb][g] = __builtin_amdgcn_mfma_f32_16x16x32_f16(af[mb][kt], Wrf[g][kt], acc[mb][g], 0, 0, 0);

  // part[ks][batch-block 0..3][gate*16+col][batch-in-block], pad 21 (R19)
  __shared__ float part[4][4][48][21];
#pragma unroll
  for (int mb = 0; mb < 2; ++mb)
#pragma unroll
    for (int g = 0; g < 3; ++g)
      *(f32x4*)&part[ks][bh * 2 + mb][g * 16 + l15][l4h * 4] = acc[mb][g];
  __syncthreads();

  // final reduce: 512 threads x 2 outputs (batches rb and rb+32)
  const int rb = tid >> 4, rd = tid & 15;
#pragma unroll
  for (int H = 0; H < 2; ++H) {
    const int b = rb + H * 32;
    const int e = b >> 4, brow = b & 15;
    const size_t xrow = ((size_t)b * L_ + t) * N3_ + d0 + rd;
    float fv = (float)xproj[xrow];
    float ov = (float)xproj[xrow + D_];
    float gv = (float)xproj[xrow + 2 * D_];
#pragma unroll
    for (int k = 0; k < 4; ++k) {
      fv += part[k][e][rd][brow];
      ov += part[k][e][16 + rd][brow];
      gv += part[k][e][32 + rd][brow];
    }
    const size_t cidx = (size_t)b * D_ + d0 + rd;
    float c = cst[cidx];
    const float sf = sigmoidf_fast(fv);
    c = c * sf + (1.f - sf) * tanhf_fast(gv);
    const float h = sigmoidf_fast(ov) * tanhf_fast(c);
    cst[cidx] = c;
    hn[cidx] = (_Float16)h;
    out[((size_t)b * L_ + t) * D_ + d0 + rd] = h;
  }
}

// ---------------------------------------------------------------------------
extern "C" void kernel_launch(void* const* d_in, const int* in_sizes, int n_in,
                              void* d_out, int out_size, void* d_ws, size_t ws_size,
                              hipStream_t stream) {
  const float* x  = (const float*)d_in[0];
  const float* Wk = (const float*)d_in[1];
  const float* Wr = (const float*)d_in[2];
  const float* c0 = (const float*)d_in[3];
  const float* h0 = (const float*)d_in[4];
  float* out = (float*)d_out;

  char* ws = (char*)d_ws;
  _Float16* WkT   = (_Float16*)(ws + WKT_OFF);
  _Float16* WrT   = (_Float16*)(ws + WRT_OFF);
  _Float16* xh    = (_Float16*)(ws + XH_OFF);
  _Float16* h16   = (_Float16*)(ws + H16_OFF);
  float*    cst   = (float*)(ws + CST_OFF);
  _Float16* xproj = (_Float16*)(ws + XPROJ_OFF);

  hipLaunchKernelGGL(transpose_f16, dim3(6144), dim3(256), 0, stream,
                     Wk, Wr, WkT, WrT);
  hipLaunchKernelGGL(convert_inputs, dim3(2048), dim3(256), 0, stream,
                     (const f32x4*)x, (const f32x4*)h0, (const f32x4*)c0,
                     (half4*)xh, (half4*)h16, (half4*)(h16 + B_ * D_),
                     (f32x4*)cst);
  hipLaunchKernelGGL(gemm_xproj, dim3(6144), dim3(256), 0, stream,
                     xh, WkT, xproj);

  for (int t = 0; t < L_; ++t) {
    _Float16* hc = h16 + (size_t)(t & 1) * (B_ * D_);
    _Float16* hn = h16 + (size_t)((t + 1) & 1) * (B_ * D_);
    hipLaunchKernelGGL(lstm_step, dim3(64), dim3(512), 0, stream,
                       WrT, xproj, cst, out, hc, hn, t);
  }
}

// Round 23
// 3489.366 us; speedup vs baseline: 1.8799x; 1.8799x over previous
//
#include <hip/hip_runtime.h>

// ---------------------------------------------------------------------------
// LSTM scan, B=64 L=512 D=1024. Round 23 = R21 (512-step-kernel graph,
// 3.55ms best) + latency hoist in lstm_step:
//   - xproj (3 scalar f16) and cst loads issued at KERNEL ENTRY (were after
//     the LDS-reduce barrier -> ~400-900cy exposed tail latency). They are
//     independent of Wr/h/MFMA, so their latency now overlaps it.
//   - out store nontemporal (never re-read; keeps L2 clean for h/Wr).
// R22 lesson: step kernel is parallelism-bound -- keep 256 WGs x 256 thr.
// Everything else byte-identical to R21.
// ---------------------------------------------------------------------------

typedef float    f32x4 __attribute__((ext_vector_type(4)));
typedef _Float16 half8 __attribute__((ext_vector_type(8)));
typedef _Float16 half4 __attribute__((ext_vector_type(4)));

#define AS1 __attribute__((address_space(1)))
#define AS3 __attribute__((address_space(3)))

#define B_  64
#define L_  512
#define D_  1024
#define N3_ 3072

// ws layout (bytes)
#define WKT_OFF   0LL          // f16 [3072][1024]   6291456
#define WRT_OFF   6291456LL    // f16 [3072][1024]   6291456
#define XH_OFF    12582912LL   // f16 [B*L][1024]   67108864
#define H16_OFF   79691776LL   // f16 [2][64][1024]   262144
#define CST_OFF   79953920LL   // f32 [64][1024]      262144
#define XPROJ_OFF 80216064LL   // f16 [B*L][3072]   201326592

__device__ __forceinline__ float sigmoidf_fast(float x) {
  return __builtin_amdgcn_rcpf(1.f + __builtin_amdgcn_exp2f(-1.4426950408889634f * x));
}
__device__ __forceinline__ float tanhf_fast(float x) {
  return 1.f - 2.f * __builtin_amdgcn_rcpf(1.f + __builtin_amdgcn_exp2f(2.8853900817779268f * x));
}

__device__ __forceinline__ void gload_lds16(const void* g, void* l) {
  __builtin_amdgcn_global_load_lds((const AS1 unsigned int*)g,
                                   (AS3 unsigned int*)l, 16, 0, 0);
}

// ---------------- prep: transpose + f32->f16 (Wk and Wr) -------------------
__global__ __launch_bounds__(256) void transpose_f16(
    const float* __restrict__ Wk, const float* __restrict__ Wr,
    _Float16* __restrict__ WkT, _Float16* __restrict__ WrT)
{
  __shared__ float tile[32][33];
  int b = blockIdx.x;
  const float* in = Wk; _Float16* outp = WkT;
  if (b >= 3072) { b -= 3072; in = Wr; outp = WrT; }
  const int n0 = (b % 96) * 32;
  const int k0 = (b / 96) * 32;
  const int tx = threadIdx.x & 31, ty = threadIdx.x >> 5;
#pragma unroll
  for (int i = 0; i < 32; i += 8)
    tile[ty + i][tx] = in[(size_t)(k0 + ty + i) * N3_ + n0 + tx];
  __syncthreads();
#pragma unroll
  for (int i = 0; i < 32; i += 8)
    outp[(size_t)(n0 + ty + i) * D_ + k0 + tx] = (_Float16)tile[tx][ty + i];
}

// ---------------- prep: x -> f16, h0 -> BOTH h16 buffers, c0 -> cst --------
__global__ void convert_inputs(const f32x4* __restrict__ x, const f32x4* __restrict__ h0,
                               const f32x4* __restrict__ c0,
                               half4* __restrict__ xh, half4* __restrict__ h16a,
                               half4* __restrict__ h16b, f32x4* __restrict__ cst)
{
  const int NX = (B_ * L_ * D_) / 4;
  const int NH = (B_ * D_) / 4;
  for (int i = blockIdx.x * blockDim.x + threadIdx.x; i < NX + NH;
       i += gridDim.x * blockDim.x) {
    if (i < NX) {
      xh[i] = __builtin_convertvector(x[i], half4);
    } else {
      const int k = i - NX;
      half4 v = __builtin_convertvector(h0[k], half4);
      h16a[k] = v;
      h16b[k] = v;
      cst[k] = c0[k];          // re-seed c every call (in-place updates)
    }
  }
}

// ---------------- xproj GEMM (R7-fixed swizzle, replay-proven) -------------
__global__ __launch_bounds__(256) void gemm_xproj(
    const _Float16* __restrict__ A,    // [32768][1024]
    const _Float16* __restrict__ BT,   // [3072][1024]
    _Float16* __restrict__ C)          // [32768][3072] f16
{
  __shared__ _Float16 As[128 * 32];
  __shared__ _Float16 Bs[128 * 32];
  const int tid = threadIdx.x, wave = tid >> 6, lane = tid & 63;
  const int mt = blockIdx.x / 24, ntile = blockIdx.x % 24;
  const int m0 = mt * 128, n0 = ntile * 128;
  const int l15 = lane & 15, l4h = lane >> 4;
  const int wm = (wave >> 1) * 64, wn = (wave & 1) * 64;

  const int c0i = wave * 2;
  const int lrow = lane >> 2;                       // 0..15 within chunk
  const int skel = 8 * ((lane & 3) ^ (lrow & 3));   // 2-bit XOR, in-bounds

  f32x4 acc[4][4];
#pragma unroll
  for (int i = 0; i < 4; ++i)
#pragma unroll
    for (int j = 0; j < 4; ++j) { f32x4 z = {0.f,0.f,0.f,0.f}; acc[i][j] = z; }

  for (int kk = 0; kk < 32; ++kk) {
    __syncthreads();
#pragma unroll
    for (int i = 0; i < 2; ++i) {
      const int c = c0i + i;
      const int row = c * 16 + lrow;
      gload_lds16(A  + (((size_t)(m0 + row)) << 10) + (kk << 5) + skel, &As[c << 9]);
      gload_lds16(BT + (((size_t)(n0 + row)) << 10) + (kk << 5) + skel, &Bs[c << 9]);
    }
    __syncthreads();
    half8 af[4], bf[4];
#pragma unroll
    for (int i = 0; i < 4; ++i) {
      const int ar = wm + i * 16 + l15;
      af[i] = *(const half8*)&As[(ar << 5) + ((l4h ^ (ar & 3)) << 3)];
      const int br = wn + i * 16 + l15;
      bf[i] = *(const half8*)&Bs[(br << 5) + ((l4h ^ (br & 3)) << 3)];
    }
#pragma unroll
    for (int i = 0; i < 4; ++i)
#pragma unroll
      for (int j = 0; j < 4; ++j)
        acc[i][j] = __builtin_amdgcn_mfma_f32_16x16x32_f16(af[i], bf[j], acc[i][j], 0, 0, 0);
  }
#pragma unroll
  for (int i = 0; i < 4; ++i) {
    const int row = m0 + wm + i * 16 + l4h * 4;
#pragma unroll
    for (int j = 0; j < 4; ++j) {
      const int col = n0 + wn + j * 16 + l15;
      _Float16* cp = C + (size_t)row * N3_ + col;
#pragma unroll
      for (int r = 0; r < 4; ++r)
        __builtin_nontemporal_store((_Float16)acc[i][j][r], cp + (size_t)r * N3_);
    }
  }
}

// ---------------- one scan step (kernel boundary = barrier) ----------------
// 256 WGs = 4 b-groups x 64 d-slices (16 cols); 4 waves own K-slices of 256.
__global__ __launch_bounds__(256) void lstm_step(
    const _Float16* __restrict__ WrT,   // [3072][1024]
    const _Float16* __restrict__ xproj, // [B*L][3072]
    float*          __restrict__ cst,   // [64][1024] in-place
    float*          __restrict__ out,   // [64][512][1024]
    const _Float16* __restrict__ hc,    // h_t
    _Float16*       __restrict__ hn,    // h_{t+1}
    int t)
{
  const int tid = threadIdx.x, wave = tid >> 6, lane = tid & 63;
  const int bid = blockIdx.x;
  const int grp = bid & 3;
  const int ord = bid >> 2;          // 0..63
  const int b0 = grp * 16;
  const int d0 = ord * 16;
  const int l15 = lane & 15, l4h = lane >> 4;
  const int kbase = wave * 256;

  // ---- HOISTED independent tail loads: xproj biases + c state ----
  const int rb = tid >> 4, rd = tid & 15;
  const size_t xrow = ((size_t)(b0 + rb) * L_ + t) * N3_ + d0 + rd;
  const float xf = (float)xproj[xrow];
  const float xo = (float)xproj[xrow + D_];
  const float xg = (float)xproj[xrow + 2 * D_];
  const size_t cidx = (size_t)(b0 + rb) * D_ + d0 + rd;
  float c = cst[cidx];

  // Wr fragments (plain loads; L2/LLC-hot after step 0)
  half8 Wrf[3][8];
#pragma unroll
  for (int g = 0; g < 3; ++g) {
    const _Float16* rr = WrT + (size_t)(g * D_ + d0 + l15) * D_ + kbase + l4h * 8;
#pragma unroll
    for (int kt = 0; kt < 8; ++kt) Wrf[g][kt] = *(const half8*)(rr + kt * 32);
  }

  // h fragments
  half8 af[8];
  const _Float16* hrow = hc + (size_t)(b0 + l15) * D_ + kbase + l4h * 8;
#pragma unroll
  for (int kt = 0; kt < 8; ++kt) af[kt] = *(const half8*)(hrow + kt * 32);

  f32x4 acc[3];
#pragma unroll
  for (int g = 0; g < 3; ++g) { f32x4 z = {0.f,0.f,0.f,0.f}; acc[g] = z; }
#pragma unroll
  for (int kt = 0; kt < 8; ++kt)
#pragma unroll
    for (int g = 0; g < 3; ++g)
      acc[g] = __builtin_amdgcn_mfma_f32_16x16x32_f16(af[kt], Wrf[g][kt], acc[g], 0, 0, 0);

  __shared__ float part[4][48][20];
#pragma unroll
  for (int g = 0; g < 3; ++g)
    *(f32x4*)&part[wave][g * 16 + l15][l4h * 4] = acc[g];
  __syncthreads();

  float fv = xf, ov = xo, gv = xg;
#pragma unroll
  for (int w = 0; w < 4; ++w) {
    fv += part[w][rd][rb];
    ov += part[w][16 + rd][rb];
    gv += part[w][32 + rd][rb];
  }
  const float sf = sigmoidf_fast(fv);
  c = c * sf + (1.f - sf) * tanhf_fast(gv);
  const float h = sigmoidf_fast(ov) * tanhf_fast(c);
  cst[cidx] = c;
  hn[cidx] = (_Float16)h;
  __builtin_nontemporal_store(h, out + ((size_t)(b0 + rb) * L_ + t) * D_ + d0 + rd);
}

// ---------------------------------------------------------------------------
extern "C" void kernel_launch(void* const* d_in, const int* in_sizes, int n_in,
                              void* d_out, int out_size, void* d_ws, size_t ws_size,
                              hipStream_t stream) {
  const float* x  = (const float*)d_in[0];
  const float* Wk = (const float*)d_in[1];
  const float* Wr = (const float*)d_in[2];
  const float* c0 = (const float*)d_in[3];
  const float* h0 = (const float*)d_in[4];
  float* out = (float*)d_out;

  char* ws = (char*)d_ws;
  _Float16* WkT   = (_Float16*)(ws + WKT_OFF);
  _Float16* WrT   = (_Float16*)(ws + WRT_OFF);
  _Float16* xh    = (_Float16*)(ws + XH_OFF);
  _Float16* h16   = (_Float16*)(ws + H16_OFF);
  float*    cst   = (float*)(ws + CST_OFF);
  _Float16* xproj = (_Float16*)(ws + XPROJ_OFF);

  hipLaunchKernelGGL(transpose_f16, dim3(6144), dim3(256), 0, stream,
                     Wk, Wr, WkT, WrT);
  hipLaunchKernelGGL(convert_inputs, dim3(2048), dim3(256), 0, stream,
                     (const f32x4*)x, (const f32x4*)h0, (const f32x4*)c0,
                     (half4*)xh, (half4*)h16, (half4*)(h16 + B_ * D_),
                     (f32x4*)cst);
  hipLaunchKernelGGL(gemm_xproj, dim3(6144), dim3(256), 0, stream,
                     xh, WkT, xproj);

  for (int t = 0; t < L_; ++t) {
    _Float16* hc = h16 + (size_t)(t & 1) * (B_ * D_);
    _Float16* hn = h16 + (size_t)((t + 1) & 1) * (B_ * D_);
    hipLaunchKernelGGL(lstm_step, dim3(256), dim3(256), 0, stream,
                       WrT, xproj, cst, out, hc, hn, t);
  }
}

// Round 24
// 3489.333 us; speedup vs baseline: 1.8799x; 1.0000x over previous
//
#include <hip/hip_runtime.h>

// ---------------------------------------------------------------------------
// LSTM scan, B=64 L=512 D=1024. Round 24 = R23 (3.49ms best) + prep polish:
//   1. transpose_f16 + convert_inputs FUSED (8192 blocks, branch on bid):
//      they were independent but serialized with a dispatch gap.
//   2. gemm_xproj: XCD-aware block swizzle (bid_sw = (bid&7)*768 + bid>>3,
//      6144%8==0 -> bijective): each XCD owns a contiguous 32-mt chunk ->
//      A-panel LLC replication 8x -> 1x.
//   3. lstm_step byte-identical to R23 (512-node graph = proven best scan:
//      two structure classes converged at ~6us/step device-sync floor).
// ---------------------------------------------------------------------------

typedef float    f32x4 __attribute__((ext_vector_type(4)));
typedef _Float16 half8 __attribute__((ext_vector_type(8)));
typedef _Float16 half4 __attribute__((ext_vector_type(4)));

#define AS1 __attribute__((address_space(1)))
#define AS3 __attribute__((address_space(3)))

#define B_  64
#define L_  512
#define D_  1024
#define N3_ 3072

// ws layout (bytes)
#define WKT_OFF   0LL          // f16 [3072][1024]   6291456
#define WRT_OFF   6291456LL    // f16 [3072][1024]   6291456
#define XH_OFF    12582912LL   // f16 [B*L][1024]   67108864
#define H16_OFF   79691776LL   // f16 [2][64][1024]   262144
#define CST_OFF   79953920LL   // f32 [64][1024]      262144
#define XPROJ_OFF 80216064LL   // f16 [B*L][3072]   201326592

__device__ __forceinline__ float sigmoidf_fast(float x) {
  return __builtin_amdgcn_rcpf(1.f + __builtin_amdgcn_exp2f(-1.4426950408889634f * x));
}
__device__ __forceinline__ float tanhf_fast(float x) {
  return 1.f - 2.f * __builtin_amdgcn_rcpf(1.f + __builtin_amdgcn_exp2f(2.8853900817779268f * x));
}

__device__ __forceinline__ void gload_lds16(const void* g, void* l) {
  __builtin_amdgcn_global_load_lds((const AS1 unsigned int*)g,
                                   (AS3 unsigned int*)l, 16, 0, 0);
}

// ---------------- prep (fused): transpose Wk/Wr + convert x/h0/c0 ----------
__global__ __launch_bounds__(256) void prep_fused(
    const float* __restrict__ Wk, const float* __restrict__ Wr,
    _Float16* __restrict__ WkT, _Float16* __restrict__ WrT,
    const f32x4* __restrict__ x, const f32x4* __restrict__ h0,
    const f32x4* __restrict__ c0,
    half4* __restrict__ xh, half4* __restrict__ h16a,
    half4* __restrict__ h16b, f32x4* __restrict__ cst)
{
  if (blockIdx.x < 6144) {
    // ---- transpose + f32->f16 ----
    __shared__ float tile[32][33];
    int b = blockIdx.x;
    const float* in = Wk; _Float16* outp = WkT;
    if (b >= 3072) { b -= 3072; in = Wr; outp = WrT; }
    const int n0 = (b % 96) * 32;
    const int k0 = (b / 96) * 32;
    const int tx = threadIdx.x & 31, ty = threadIdx.x >> 5;
#pragma unroll
    for (int i = 0; i < 32; i += 8)
      tile[ty + i][tx] = in[(size_t)(k0 + ty + i) * N3_ + n0 + tx];
    __syncthreads();
#pragma unroll
    for (int i = 0; i < 32; i += 8)
      outp[(size_t)(n0 + ty + i) * D_ + k0 + tx] = (_Float16)tile[tx][ty + i];
  } else {
    // ---- convert x -> f16, seed h buffers and c state ----
    const int NX = (B_ * L_ * D_) / 4;
    const int NH = (B_ * D_) / 4;
    for (int i = (blockIdx.x - 6144) * blockDim.x + threadIdx.x; i < NX + NH;
         i += 2048 * blockDim.x) {
      if (i < NX) {
        xh[i] = __builtin_convertvector(x[i], half4);
      } else {
        const int k = i - NX;
        half4 v = __builtin_convertvector(h0[k], half4);
        h16a[k] = v;
        h16b[k] = v;
        cst[k] = c0[k];        // re-seed c every call (in-place updates)
      }
    }
  }
}

// ---------------- xproj GEMM (R7-fixed swizzle + XCD-aware blocks) ---------
__global__ __launch_bounds__(256) void gemm_xproj(
    const _Float16* __restrict__ A,    // [32768][1024]
    const _Float16* __restrict__ BT,   // [3072][1024]
    _Float16* __restrict__ C)          // [32768][3072] f16
{
  __shared__ _Float16 As[128 * 32];
  __shared__ _Float16 Bs[128 * 32];
  const int tid = threadIdx.x, wave = tid >> 6, lane = tid & 63;
  // XCD swizzle: 6144 blocks = 8 XCDs x 768; each XCD gets contiguous tiles
  const int bsw = (blockIdx.x & 7) * 768 + (blockIdx.x >> 3);
  const int mt = bsw / 24, ntile = bsw % 24;
  const int m0 = mt * 128, n0 = ntile * 128;
  const int l15 = lane & 15, l4h = lane >> 4;
  const int wm = (wave >> 1) * 64, wn = (wave & 1) * 64;

  const int c0i = wave * 2;
  const int lrow = lane >> 2;                       // 0..15 within chunk
  const int skel = 8 * ((lane & 3) ^ (lrow & 3));   // 2-bit XOR, in-bounds

  f32x4 acc[4][4];
#pragma unroll
  for (int i = 0; i < 4; ++i)
#pragma unroll
    for (int j = 0; j < 4; ++j) { f32x4 z = {0.f,0.f,0.f,0.f}; acc[i][j] = z; }

  for (int kk = 0; kk < 32; ++kk) {
    __syncthreads();
#pragma unroll
    for (int i = 0; i < 2; ++i) {
      const int c = c0i + i;
      const int row = c * 16 + lrow;
      gload_lds16(A  + (((size_t)(m0 + row)) << 10) + (kk << 5) + skel, &As[c << 9]);
      gload_lds16(BT + (((size_t)(n0 + row)) << 10) + (kk << 5) + skel, &Bs[c << 9]);
    }
    __syncthreads();
    half8 af[4], bf[4];
#pragma unroll
    for (int i = 0; i < 4; ++i) {
      const int ar = wm + i * 16 + l15;
      af[i] = *(const half8*)&As[(ar << 5) + ((l4h ^ (ar & 3)) << 3)];
      const int br = wn + i * 16 + l15;
      bf[i] = *(const half8*)&Bs[(br << 5) + ((l4h ^ (br & 3)) << 3)];
    }
#pragma unroll
    for (int i = 0; i < 4; ++i)
#pragma unroll
      for (int j = 0; j < 4; ++j)
        acc[i][j] = __builtin_amdgcn_mfma_f32_16x16x32_f16(af[i], bf[j], acc[i][j], 0, 0, 0);
  }
#pragma unroll
  for (int i = 0; i < 4; ++i) {
    const int row = m0 + wm + i * 16 + l4h * 4;
#pragma unroll
    for (int j = 0; j < 4; ++j) {
      const int col = n0 + wn + j * 16 + l15;
      _Float16* cp = C + (size_t)row * N3_ + col;
#pragma unroll
      for (int r = 0; r < 4; ++r)
        __builtin_nontemporal_store((_Float16)acc[i][j][r], cp + (size_t)r * N3_);
    }
  }
}

// ---------------- one scan step (kernel boundary = barrier; R23) -----------
// 256 WGs = 4 b-groups x 64 d-slices (16 cols); 4 waves own K-slices of 256.
__global__ __launch_bounds__(256) void lstm_step(
    const _Float16* __restrict__ WrT,   // [3072][1024]
    const _Float16* __restrict__ xproj, // [B*L][3072]
    float*          __restrict__ cst,   // [64][1024] in-place
    float*          __restrict__ out,   // [64][512][1024]
    const _Float16* __restrict__ hc,    // h_t
    _Float16*       __restrict__ hn,    // h_{t+1}
    int t)
{
  const int tid = threadIdx.x, wave = tid >> 6, lane = tid & 63;
  const int bid = blockIdx.x;
  const int grp = bid & 3;
  const int ord = bid >> 2;          // 0..63
  const int b0 = grp * 16;
  const int d0 = ord * 16;
  const int l15 = lane & 15, l4h = lane >> 4;
  const int kbase = wave * 256;

  // hoisted independent tail loads: xproj biases + c state (R23)
  const int rb = tid >> 4, rd = tid & 15;
  const size_t xrow = ((size_t)(b0 + rb) * L_ + t) * N3_ + d0 + rd;
  const float xf = (float)xproj[xrow];
  const float xo = (float)xproj[xrow + D_];
  const float xg = (float)xproj[xrow + 2 * D_];
  const size_t cidx = (size_t)(b0 + rb) * D_ + d0 + rd;
  float c = cst[cidx];

  // Wr fragments (plain loads; L2-hot across steps)
  half8 Wrf[3][8];
#pragma unroll
  for (int g = 0; g < 3; ++g) {
    const _Float16* rr = WrT + (size_t)(g * D_ + d0 + l15) * D_ + kbase + l4h * 8;
#pragma unroll
    for (int kt = 0; kt < 8; ++kt) Wrf[g][kt] = *(const half8*)(rr + kt * 32);
  }

  // h fragments
  half8 af[8];
  const _Float16* hrow = hc + (size_t)(b0 + l15) * D_ + kbase + l4h * 8;
#pragma unroll
  for (int kt = 0; kt < 8; ++kt) af[kt] = *(const half8*)(hrow + kt * 32);

  f32x4 acc[3];
#pragma unroll
  for (int g = 0; g < 3; ++g) { f32x4 z = {0.f,0.f,0.f,0.f}; acc[g] = z; }
#pragma unroll
  for (int kt = 0; kt < 8; ++kt)
#pragma unroll
    for (int g = 0; g < 3; ++g)
      acc[g] = __builtin_amdgcn_mfma_f32_16x16x32_f16(af[kt], Wrf[g][kt], acc[g], 0, 0, 0);

  __shared__ float part[4][48][20];
#pragma unroll
  for (int g = 0; g < 3; ++g)
    *(f32x4*)&part[wave][g * 16 + l15][l4h * 4] = acc[g];
  __syncthreads();

  float fv = xf, ov = xo, gv = xg;
#pragma unroll
  for (int w = 0; w < 4; ++w) {
    fv += part[w][rd][rb];
    ov += part[w][16 + rd][rb];
    gv += part[w][32 + rd][rb];
  }
  const float sf = sigmoidf_fast(fv);
  c = c * sf + (1.f - sf) * tanhf_fast(gv);
  const float h = sigmoidf_fast(ov) * tanhf_fast(c);
  cst[cidx] = c;
  hn[cidx] = (_Float16)h;
  __builtin_nontemporal_store(h, out + ((size_t)(b0 + rb) * L_ + t) * D_ + d0 + rd);
}

// ---------------------------------------------------------------------------
extern "C" void kernel_launch(void* const* d_in, const int* in_sizes, int n_in,
                              void* d_out, int out_size, void* d_ws, size_t ws_size,
                              hipStream_t stream) {
  const float* x  = (const float*)d_in[0];
  const float* Wk = (const float*)d_in[1];
  const float* Wr = (const float*)d_in[2];
  const float* c0 = (const float*)d_in[3];
  const float* h0 = (const float*)d_in[4];
  float* out = (float*)d_out;

  char* ws = (char*)d_ws;
  _Float16* WkT   = (_Float16*)(ws + WKT_OFF);
  _Float16* WrT   = (_Float16*)(ws + WRT_OFF);
  _Float16* xh    = (_Float16*)(ws + XH_OFF);
  _Float16* h16   = (_Float16*)(ws + H16_OFF);
  float*    cst   = (float*)(ws + CST_OFF);
  _Float16* xproj = (_Float16*)(ws + XPROJ_OFF);

  hipLaunchKernelGGL(prep_fused, dim3(8192), dim3(256), 0, stream,
                     Wk, Wr, WkT, WrT,
                     (const f32x4*)x, (const f32x4*)h0, (const f32x4*)c0,
                     (half4*)xh, (half4*)h16, (half4*)(h16 + B_ * D_),
                     (f32x4*)cst);
  hipLaunchKernelGGL(gemm_xproj, dim3(6144), dim3(256), 0, stream,
                     xh, WkT, xproj);

  for (int t = 0; t < L_; ++t) {
    _Float16* hc = h16 + (size_t)(t & 1) * (B_ * D_);
    _Float16* hn = h16 + (size_t)((t + 1) & 1) * (B_ * D_);
    hipLaunchKernelGGL(lstm_step, dim3(256), dim3(256), 0, stream,
                       WrT, xproj, cst, out, hc, hn, t);
  }
}